// Round 1
// 582.588 us; speedup vs baseline: 1.0081x; 1.0081x over previous
//
#include <hip/hip_runtime.h>
#include <math.h>

#define E_ 4
#define B_ 128
#define Q_ 900
#define C_ 256
#define H_ 16
#define QC (Q_ * C_)   // 230400

typedef float f4_t __attribute__((ext_vector_type(4)));

// ---------------------------------------------------------------------------
// Kernel 1: expert_probs[b,e] = sigmoid(mean_q logits[e,b,q,0])
// One block of 256 threads per (e,b) pair -> 512 blocks = 2048 waves (8/CU).
// Strided 1KiB reads; nontemporal (touch-once lines, no reuse by combine's
// own nontemporal reads).
// ---------------------------------------------------------------------------
__global__ __launch_bounds__(256) void probs_kernel(
        const float* __restrict__ logits,
        float* __restrict__ out_probs) {
    __shared__ float red[4];
    int eb = blockIdx.x;          // eb = e*B + b  (matches memory layout)
    int e  = eb / B_;
    int b  = eb % B_;
    const float* base = logits + (size_t)eb * QC;
    int t = threadIdx.x;          // 0..255

    float s = 0.f;
    #pragma unroll
    for (int q = t; q < Q_; q += 256)      // q = t, t+256, t+512, t+768
        s += __builtin_nontemporal_load(base + (size_t)q * C_);

    // wave-64 reduction
    #pragma unroll
    for (int off = 32; off > 0; off >>= 1)
        s += __shfl_down(s, off, 64);

    int wave = t >> 6;
    if ((t & 63) == 0) red[wave] = s;
    __syncthreads();
    if (t == 0) {
        float tot = red[0] + red[1] + red[2] + red[3];
        float m = tot * (1.0f / (float)Q_);
        out_probs[b * E_ + e] = 1.0f / (1.0f + expf(-m));
    }
}

// ---------------------------------------------------------------------------
// Kernel 2 (fused): gating MLP + softmax + top-2 + renormalize recomputed
// per block (thread 0, ~200 flops, LDS broadcast) + streaming combine.
// Grid (75, B), block 256, 3 x float4 per thread: 75*256*3 = 57600 = QC/4.
// Block (0,b) additionally writes the small outputs (norm_w/final/topidx).
// All bulk traffic is touch-once -> nontemporal.
// ---------------------------------------------------------------------------
__global__ __launch_bounds__(256) void gate_combine_kernel(
        const float* __restrict__ logits,
        const float* __restrict__ probs,   // [B,E]
        const float* __restrict__ W1,      // [E,H]
        const float* __restrict__ b1,      // [H]
        const float* __restrict__ W2,      // [H,E]
        const float* __restrict__ b2,      // [E]
        float* __restrict__ out_comb,      // [B,Q,C]
        float* __restrict__ out_final,     // [B]
        float* __restrict__ out_norm_w,    // [B,E]
        float* __restrict__ out_topidx) {  // [B,2] (as float)
    __shared__ float sw[2];
    __shared__ int   si[2];
    int b = blockIdx.y;

    if (threadIdx.x == 0) {
        float p[E_];
        #pragma unroll
        for (int e = 0; e < E_; e++) p[e] = probs[b * E_ + e];

        // h = relu(p @ W1 + b1)
        float h[H_];
        #pragma unroll
        for (int j = 0; j < H_; j++) {
            float a = b1[j];
            #pragma unroll
            for (int e = 0; e < E_; e++) a += p[e] * W1[e * H_ + j];
            h[j] = fmaxf(a, 0.f);
        }

        // logits = h @ W2 + b2 ; softmax
        float w[E_];
        float mx = -1e30f;
        #pragma unroll
        for (int e = 0; e < E_; e++) {
            float a = b2[e];
            #pragma unroll
            for (int j = 0; j < H_; j++) a += h[j] * W2[j * E_ + e];
            w[e] = a;
            mx = fmaxf(mx, a);
        }
        float sum = 0.f;
        #pragma unroll
        for (int e = 0; e < E_; e++) { w[e] = expf(w[e] - mx); sum += w[e]; }
        float inv = 1.0f / sum;
        #pragma unroll
        for (int e = 0; e < E_; e++) w[e] *= inv;

        // top-2 (strict > keeps lowest index on ties, matching jax.lax.top_k)
        int i0 = 0;
        #pragma unroll
        for (int e = 1; e < E_; e++) if (w[e] > w[i0]) i0 = e;
        int i1 = -1;
        #pragma unroll
        for (int e = 0; e < E_; e++)
            if (e != i0 && (i1 < 0 || w[e] > w[i1])) i1 = e;

        float s2  = w[i0] + w[i1] + 1e-8f;
        float nw0 = w[i0] / s2;
        float nw1 = w[i1] / s2;

        sw[0] = nw0; sw[1] = nw1;
        si[0] = i0;  si[1] = i1;

        if (blockIdx.x == 0) {
            #pragma unroll
            for (int e = 0; e < E_; e++) out_norm_w[b * E_ + e] = 0.f;
            out_norm_w[b * E_ + i0] = nw0;
            out_norm_w[b * E_ + i1] = nw1;
            out_final[b] = nw0 * p[i0] + nw1 * p[i1];
            out_topidx[b * 2 + 0] = (float)i0;
            out_topidx[b * 2 + 1] = (float)i1;
        }
    }
    __syncthreads();

    float w0 = sw[0], w1 = sw[1];
    const f4_t* s0 = (const f4_t*)(logits + (size_t)(si[0] * B_ + b) * QC);
    const f4_t* s1 = (const f4_t*)(logits + (size_t)(si[1] * B_ + b) * QC);
    f4_t*       o  = (f4_t*)(out_comb + (size_t)b * QC);

    int base = blockIdx.x * 768 + threadIdx.x;   // 3 f4 per thread
    #pragma unroll
    for (int k = 0; k < 3; k++) {
        int idx = base + k * 256;
        f4_t a = __builtin_nontemporal_load(s0 + idx);
        f4_t c = __builtin_nontemporal_load(s1 + idx);
        f4_t r = w0 * a + w1 * c;
        __builtin_nontemporal_store(r, o + idx);
    }
}

// ---------------------------------------------------------------------------
extern "C" void kernel_launch(void* const* d_in, const int* in_sizes, int n_in,
                              void* d_out, int out_size, void* d_ws, size_t ws_size,
                              hipStream_t stream) {
    const float* logits = (const float*)d_in[0];  // [E,B,Q,C]
    const float* W1     = (const float*)d_in[1];  // [E,H]
    const float* b1     = (const float*)d_in[2];  // [H]
    const float* W2     = (const float*)d_in[3];  // [H,E]
    const float* b2     = (const float*)d_in[4];  // [E]

    float* out          = (float*)d_out;
    float* out_combined = out;                            // B*Q*C
    float* out_final    = out_combined + (size_t)B_ * QC; // B
    float* out_norm_w   = out_final + B_;                 // B*E
    float* out_probs    = out_norm_w + B_ * E_;           // B*E
    float* out_topidx   = out_probs + B_ * E_;            // B*2

    probs_kernel<<<E_ * B_, 256, 0, stream>>>(logits, out_probs);
    gate_combine_kernel<<<dim3(75, B_), 256, 0, stream>>>(
        logits, out_probs, W1, b1, W2, b2,
        out_combined, out_final, out_norm_w, out_topidx);
}